// Round 9
// baseline (177.218 us; speedup 1.0000x reference)
//
#include <hip/hip_runtime.h>
#include <stdint.h>

#define NSEQ 2048

typedef __attribute__((ext_vector_type(4))) float f32x4;
typedef __attribute__((ext_vector_type(8))) short s16x8;
typedef _Float16 f16x8 __attribute__((ext_vector_type(8)));

// workspace byte offsets
#define OFF_XT  0u            // [3][4][2048][256] f16 = 12 MB (dead after k_proj)
#define OFF_PO  0u            // [4 split][16 bh][2048][64] f16 = 16 MB (aliases dead XT)
#define OFF_M   16777216u     // [4][16][2048] f32 running-max (log2 domain), 512 KB
#define OFF_L   17301504u     // [4][16][2048] f32 running-sum, 512 KB
#define OFF_QR  17825792u     // [16][2048][64] f16, 4 MB
#define OFF_KR  22020096u     // [16][2048][64]
#define OFF_VT  26214400u     // [16][64][2048]   (ws end ~29 MB)

__device__ __forceinline__ short f2h(float f) {
  _Float16 h = (_Float16)f;
  return __builtin_bit_cast(short, h);
}
__device__ __forceinline__ float h2f(short s) {
  return (float)__builtin_bit_cast(_Float16, s);
}
// 128B-row tiles ([*][64] f16): classic ^(row&7) on the 16B slot
__device__ __forceinline__ int swz128(int row, int slot) {
  return row * 128 + ((slot ^ (row & 7)) << 4);
}
#define MFMA(a, b, c) __builtin_amdgcn_mfma_f32_16x16x32_f16(a, b, c, 0, 0, 0)

// ---------------- kernel 1: transpose-cast q/k/v [b][i][n] f32 -> [b][n][i] f16 ------
__global__ __launch_bounds__(256) void k_trans(const float* __restrict__ q,
    const float* __restrict__ k, const float* __restrict__ v, char* __restrict__ ws) {
  int tensor = blockIdx.z >> 2, b = blockIdx.z & 3;
  const float* src = tensor == 0 ? q : (tensor == 1 ? k : v);
  short* dst = (short*)(ws + OFF_XT) + (tensor * 4 + b) * 524288;
  int n0 = blockIdx.x * 64, i0 = blockIdx.y * 64;
  __shared__ float tile[64][65];
  int t = threadIdx.x;
  int nl = t & 63, ib = (t >> 6) * 16;
#pragma unroll
  for (int r = 0; r < 16; ++r)
    tile[ib + r][nl] = src[(b * 256 + i0 + ib + r) * 2048 + n0 + nl];
  __syncthreads();
  int nr = t >> 2, ic = (t & 3) * 16;
  short tmp[16];
#pragma unroll
  for (int j = 0; j < 16; ++j) tmp[j] = f2h(tile[ic + j][nr]);
  short* dp = &dst[(n0 + nr) * 256 + i0 + ic];
  *(s16x8*)dp = *(const s16x8*)&tmp[0];
  *(s16x8*)(dp + 8) = *(const s16x8*)&tmp[8];
}

// ------- kernel 2: QKV projection (64x64 tile, W cast fused) + bias + RoPE ----------
// XCD chunk-swizzle: y (o-tile) fastest in fm so each XCD owns complete y-groups
__global__ __launch_bounds__(256) void k_proj(const float* __restrict__ Wq,
    const float* __restrict__ Wk, const float* __restrict__ Wv,
    const float* __restrict__ enc, const float* __restrict__ bq,
    const float* __restrict__ bk, const float* __restrict__ bv, char* __restrict__ ws) {
  int hid = blockIdx.x + 32 * (blockIdx.y + 4 * blockIdx.z);   // 0..1535
  int fm = (hid & 7) * 192 + (hid >> 3);                       // bijective (1536%8==0)
  int yo = fm & 3, xn = (fm >> 2) & 31, z = fm >> 7;
  int proj = z >> 2, b = z & 3;
  const float* W = proj == 0 ? Wq : (proj == 1 ? Wk : Wv);
  const short* X = (const short*)(ws + OFF_XT) + (proj * 4 + b) * 524288;
  int o0 = yo * 64, n0 = xn * 64;
  __shared__ short As[64 * 64], Bs[64 * 64];
  int t = threadIdx.x, lane = t & 63, g = lane >> 4, c = lane & 15, wave = t >> 6;
  int wr = wave >> 1, wc = wave & 1;
  int row = t >> 2, seg = t & 3;
  f32x4 acc[2][2] = {};
  for (int kk = 0; kk < 4; ++kk) {
    __syncthreads();
    int koff = kk * 64;
    // A: W f32 -> f16 in-staging (16 f16 per thread)
    const float* wsrc = &W[(o0 + row) * 256 + koff + seg * 16];
    short ha[16];
#pragma unroll
    for (int q4 = 0; q4 < 4; ++q4) {
      f32x4 wv4 = *(const f32x4*)(wsrc + q4 * 4);
#pragma unroll
      for (int j = 0; j < 4; ++j) ha[q4 * 4 + j] = f2h(wv4[j]);
    }
    *(s16x8*)((char*)As + swz128(row, seg * 2))     = *(const s16x8*)&ha[0];
    *(s16x8*)((char*)As + swz128(row, seg * 2 + 1)) = *(const s16x8*)&ha[8];
    // B from XT (f16)
    const short* xsrc = &X[(n0 + row) * 256 + koff];
    *(s16x8*)((char*)Bs + swz128(row, seg))     = *(const s16x8*)(xsrc + seg * 8);
    *(s16x8*)((char*)Bs + swz128(row, 4 + seg)) = *(const s16x8*)(xsrc + 32 + seg * 8);
    __syncthreads();
#pragma unroll
    for (int ks = 0; ks < 2; ++ks) {
      f16x8 af[2], bfr[2];
#pragma unroll
      for (int f = 0; f < 2; ++f) {
        af[f]  = *(const f16x8*)((char*)As + swz128(wr * 32 + f * 16 + c, ks * 4 + g));
        bfr[f] = *(const f16x8*)((char*)Bs + swz128(wc * 32 + f * 16 + c, ks * 4 + g));
      }
#pragma unroll
      for (int i = 0; i < 2; ++i)
#pragma unroll
        for (int j = 0; j < 2; ++j)
          acc[i][j] = MFMA(af[i], bfr[j], acc[i][j]);
    }
  }
  const float* bias = proj == 0 ? bq : (proj == 1 ? bk : bv);
  if (proj < 2) {
    // RoPE: h = reg r, d = (o>>2); pair at lane^16, same reg.
    // fold 1/sqrt(64) * log2(e) into Q so softmax runs in exp2 domain
    short* dst0 = (short*)(ws + (proj == 0 ? OFF_QR : OFF_KR));
    float scale = proj == 0 ? 0.18033688f : 1.0f;
    float sgn = (g & 1) ? 1.0f : -1.0f;
#pragma unroll
    for (int i = 0; i < 2; ++i) {
      int ob = o0 + wr * 32 + i * 16 + g * 4;
      int d = ob >> 2;
#pragma unroll
      for (int j = 0; j < 2; ++j) {
        int n = n0 + wc * 32 + j * 16 + c;
        float cv = enc[n * 64 + d], sv = enc[131072 + n * 64 + d];
#pragma unroll
        for (int r = 0; r < 4; ++r) {
          float val = acc[i][j][r] + bias[ob + r];
          float par = __shfl_xor(val, 16, 64);
          float res = (val * cv + sgn * par * sv) * scale;
          dst0[((b * 4 + r) * 2048 + n) * 64 + d] = f2h(res);  // [bh][n][d]
        }
      }
    }
  } else {
    short* dst = (short*)(ws + OFF_VT);
#pragma unroll
    for (int i = 0; i < 2; ++i) {
      int ob = o0 + wr * 32 + i * 16 + g * 4;
      int d = ob >> 2;
#pragma unroll
      for (int j = 0; j < 2; ++j) {
        int n = n0 + wc * 32 + j * 16 + c;
#pragma unroll
        for (int r = 0; r < 4; ++r) {
          float val = acc[i][j][r] + bias[ob + r];
          dst[((b * 4 + r) * 64 + d) * 2048 + n] = f2h(val);  // [bh][d][m]
        }
      }
    }
  }
}

// --- kernel 3: flash attention, split-KV x4, swapped QK^T, 32 q-rows per wave -------
__global__ __launch_bounds__(256, 4) void k_attn(char* __restrict__ ws) {
  int hid = blockIdx.x + 16 * (blockIdx.y + 16 * blockIdx.z);  // 0..1023
  int fm = (hid & 7) * 128 + (hid >> 3);                       // bijective (1024%8==0)
  int qx = fm & 15, bh = (fm >> 4) & 15, ms = fm >> 8;
  int t = threadIdx.x, wave = t >> 6, lane = t & 63, g = lane >> 4, c = lane & 15;
  int nw = qx * 128 + wave * 32;  // this wave's 32 Q rows (groups A: +c, B: +16+c)
  const short* Q = (const short*)(ws + OFF_QR) + bh * 131072;  // [2048][64]
  const short* K = (const short*)(ws + OFF_KR) + bh * 131072;
  const short* V = (const short*)(ws + OFF_VT) + bh * 131072;  // [64][2048]
  __shared__ short Ks[64 * 64], Vs[64 * 64], Ps[4][32 * 64];
  char* Pb = (char*)Ps[wave];
  f16x8 qa0 = *(const f16x8*)&Q[(nw + c) * 64 + g * 8];
  f16x8 qa1 = *(const f16x8*)&Q[(nw + c) * 64 + 32 + g * 8];
  f16x8 qb0 = *(const f16x8*)&Q[(nw + 16 + c) * 64 + g * 8];
  f16x8 qb1 = *(const f16x8*)&Q[(nw + 16 + c) * 64 + 32 + g * 8];
  f32x4 poA[4] = {}, poB[4] = {};
  float mrA = -1e30f, lrA = 0.f, mrB = -1e30f, lrB = 0.f;
  int sr = t >> 3, sl = t & 7;
  const int mb = ms * 512;
  int bsrc = g * 16 + g * 4;       // shfl base: lane in same g-group holding row g*4+r

  s16x8 RA[4], RB[4];
  auto LD = [&](int m0, s16x8* R) {
    R[0] = *(const s16x8*)&K[(m0 + sr) * 64 + sl * 8];
    R[1] = *(const s16x8*)&K[(m0 + sr + 32) * 64 + sl * 8];
    R[2] = *(const s16x8*)&V[sr * 2048 + m0 + sl * 8];
    R[3] = *(const s16x8*)&V[(sr + 32) * 2048 + m0 + sl * 8];
  };
  auto ST = [&](const s16x8* R) {
    *(s16x8*)((char*)Ks + swz128(sr, sl))      = R[0];
    *(s16x8*)((char*)Ks + swz128(sr + 32, sl)) = R[1];
    *(s16x8*)((char*)Vs + swz128(sr, sl))      = R[2];
    *(s16x8*)((char*)Vs + swz128(sr + 32, sl)) = R[3];
  };
  auto COMPUTE = [&]() {
    // S^T = K Q^T for both row-groups; K-frags shared
    f32x4 sA[4] = {}, sB[4] = {};
    __builtin_amdgcn_s_setprio(1);
#pragma unroll
    for (int fj = 0; fj < 4; ++fj) {
      f16x8 k0 = *(const f16x8*)((char*)Ks + swz128(fj * 16 + c, g));
      f16x8 k1 = *(const f16x8*)((char*)Ks + swz128(fj * 16 + c, 4 + g));
      sA[fj] = MFMA(k0, qa0, sA[fj]);
      sB[fj] = MFMA(k0, qb0, sB[fj]);
      sA[fj] = MFMA(k1, qa1, sA[fj]);
      sB[fj] = MFMA(k1, qb1, sB[fj]);
    }
    __builtin_amdgcn_s_setprio(0);
    // row-max trees (A,B independent -> ILP), then 2 cross-lane rounds each
    float a0 = fmaxf(fmaxf(sA[0][0], sA[0][1]), fmaxf(sA[0][2], sA[0][3]));
    float a1 = fmaxf(fmaxf(sA[1][0], sA[1][1]), fmaxf(sA[1][2], sA[1][3]));
    float a2 = fmaxf(fmaxf(sA[2][0], sA[2][1]), fmaxf(sA[2][2], sA[2][3]));
    float a3 = fmaxf(fmaxf(sA[3][0], sA[3][1]), fmaxf(sA[3][2], sA[3][3]));
    float b0 = fmaxf(fmaxf(sB[0][0], sB[0][1]), fmaxf(sB[0][2], sB[0][3]));
    float b1 = fmaxf(fmaxf(sB[1][0], sB[1][1]), fmaxf(sB[1][2], sB[1][3]));
    float b2 = fmaxf(fmaxf(sB[2][0], sB[2][1]), fmaxf(sB[2][2], sB[2][3]));
    float b3 = fmaxf(fmaxf(sB[3][0], sB[3][1]), fmaxf(sB[3][2], sB[3][3]));
    float rmA = fmaxf(fmaxf(a0, a1), fmaxf(a2, a3));
    float rmB = fmaxf(fmaxf(b0, b1), fmaxf(b2, b3));
    rmA = fmaxf(rmA, __shfl_xor(rmA, 16, 64));
    rmB = fmaxf(rmB, __shfl_xor(rmB, 16, 64));
    rmA = fmaxf(rmA, __shfl_xor(rmA, 32, 64));
    rmB = fmaxf(rmB, __shfl_xor(rmB, 32, 64));
    // defer-max (exp2 domain)
    if (__any(rmA > mrA + 11.5f)) {
      float nm = fmaxf(mrA, rmA);
      float corr = exp2f(mrA - nm);
      mrA = nm; lrA *= corr;
#pragma unroll
      for (int r = 0; r < 4; ++r) {
        float cr = __shfl(corr, bsrc + r, 64);
#pragma unroll
        for (int fd = 0; fd < 4; ++fd) poA[fd][r] *= cr;
      }
    }
    if (__any(rmB > mrB + 11.5f)) {
      float nm = fmaxf(mrB, rmB);
      float corr = exp2f(mrB - nm);
      mrB = nm; lrB *= corr;
#pragma unroll
      for (int r = 0; r < 4; ++r) {
        float cr = __shfl(corr, bsrc + r, 64);
#pragma unroll
        for (int fd = 0; fd < 4; ++fd) poB[fd][r] *= cr;
      }
    }
    float pA[4][4], pB[4][4], rsA = 0.f, rsB = 0.f;
#pragma unroll
    for (int fj = 0; fj < 4; ++fj)
#pragma unroll
      for (int r = 0; r < 4; ++r) {
        pA[fj][r] = exp2f(sA[fj][r] - mrA);
        pB[fj][r] = exp2f(sB[fj][r] - mrB);
        rsA += pA[fj][r];
        rsB += pB[fj][r];
      }
    rsA += __shfl_xor(rsA, 16, 64);
    rsB += __shfl_xor(rsB, 16, 64);
    rsA += __shfl_xor(rsA, 32, 64);
    rsB += __shfl_xor(rsB, 32, 64);
    lrA += rsA; lrB += rsB;
    // P^T -> Ps rows: group A at row c, group B at row 16+c
#pragma unroll
    for (int fj = 0; fj < 4; ++fj)
#pragma unroll
      for (int r = 0; r < 4; ++r) {
        int mm = fj * 16 + g * 4 + r;
        *(short*)(Pb + swz128(c, mm >> 3) + (mm & 7) * 2)      = f2h(pA[fj][r]);
        *(short*)(Pb + swz128(16 + c, mm >> 3) + (mm & 7) * 2) = f2h(pB[fj][r]);
      }
    asm volatile("s_waitcnt lgkmcnt(0)" ::: "memory");
    __builtin_amdgcn_sched_barrier(0);
    f16x8 paA0 = *(const f16x8*)(Pb + swz128(c, g));
    f16x8 paA1 = *(const f16x8*)(Pb + swz128(c, 4 + g));
    f16x8 paB0 = *(const f16x8*)(Pb + swz128(16 + c, g));
    f16x8 paB1 = *(const f16x8*)(Pb + swz128(16 + c, 4 + g));
    __builtin_amdgcn_s_setprio(1);
#pragma unroll
    for (int fd = 0; fd < 4; ++fd) {
      int dd = fd * 16 + c;
      f16x8 vb0 = *(const f16x8*)((char*)Vs + swz128(dd, g));
      f16x8 vb1 = *(const f16x8*)((char*)Vs + swz128(dd, 4 + g));
      poA[fd] = MFMA(paA0, vb0, poA[fd]);
      poB[fd] = MFMA(paB0, vb0, poB[fd]);
      poA[fd] = MFMA(paA1, vb1, poA[fd]);
      poB[fd] = MFMA(paB1, vb1, poB[fd]);
    }
    __builtin_amdgcn_s_setprio(0);
  };

  LD(mb, RA);
  for (int tt = 0; tt < 8; tt += 2) {
    __syncthreads();                 // prior tile's LDS reads complete
    ST(RA);
    LD(mb + (tt + 1) * 64, RB);      // prefetch hides under compute
    __syncthreads();
    COMPUTE();
    __syncthreads();
    ST(RB);
    if (tt + 2 < 8) LD(mb + (tt + 2) * 64, RA);
    __syncthreads();
    COMPUTE();
  }

  // write normalized partial O + (m, l) for combine
  short* PO = (short*)(ws + OFF_PO);
  float* Mm = (float*)(ws + OFF_M);
  float* Ll = (float*)(ws + OFF_L);
  int base = (ms * 16 + bh) * 2048;
  float liA[4], liB[4];
#pragma unroll
  for (int r = 0; r < 4; ++r) {
    liA[r] = 1.0f / __shfl(lrA, bsrc + r, 64);
    liB[r] = 1.0f / __shfl(lrB, bsrc + r, 64);
  }
#pragma unroll
  for (int fd = 0; fd < 4; ++fd) {
    int d = fd * 16 + c;
#pragma unroll
    for (int r = 0; r < 4; ++r) {
      int nA = nw + g * 4 + r;
      int nB = nw + 16 + g * 4 + r;
      PO[(base + nA) * 64 + d] = f2h(poA[fd][r] * liA[r]);
      PO[(base + nB) * 64 + d] = f2h(poB[fd][r] * liB[r]);
    }
  }
  if (g == 0) {
    Mm[base + nw + c] = mrA;
    Ll[base + nw + c] = lrA;
    Mm[base + nw + 16 + c] = mrB;
    Ll[base + nw + 16 + c] = lrB;
  }
}

// ------- kernel 4: output projection (64x64), split-combine fused in B-staging ------
__global__ __launch_bounds__(256) void k_final(const float* __restrict__ Wm,
    const float* __restrict__ bm, float* __restrict__ out, char* __restrict__ ws) {
  int hid = blockIdx.x + 32 * (blockIdx.y + 4 * blockIdx.z);   // 0..511
  int fm = (hid & 7) * 64 + (hid >> 3);                        // bijective (512%8==0)
  int yo = fm & 3, xn = (fm >> 2) & 31, b = fm >> 7;
  int o0 = yo * 64, n0 = xn * 64;
  const short* PO = (const short*)(ws + OFF_PO);
  const float* Mm = (const float*)(ws + OFF_M);
  const float* Ll = (const float*)(ws + OFF_L);
  __shared__ short As[64 * 64], Bs[64 * 64];
  int t = threadIdx.x, lane = t & 63, g = lane >> 4, c = lane & 15, wave = t >> 6;
  int wr = wave >> 1, wc = wave & 1;
  int row = t >> 2, seg = t & 3;
  f32x4 acc[2][2] = {};
  for (int kk = 0; kk < 4; ++kk) {   // kk = head h; local k = d within head
    __syncthreads();
    // A: Wm gather-reorder (Wm_r[o][h*64+d] = Wm[o][d*4+h]) + f32->f16
    short ha[16];
#pragma unroll
    for (int j = 0; j < 16; ++j)
      ha[j] = f2h(Wm[(o0 + row) * 256 + (seg * 16 + j) * 4 + kk]);
    *(s16x8*)((char*)As + swz128(row, seg * 2))     = *(const s16x8*)&ha[0];
    *(s16x8*)((char*)As + swz128(row, seg * 2 + 1)) = *(const s16x8*)&ha[8];
    // B: combine 4 KV-split partials for rows n0+row, head kk, d = seg*16..+16
    int bh = b * 4 + kk;
    int nr = n0 + row;
    float m0 = Mm[(0 * 16 + bh) * 2048 + nr], l0 = Ll[(0 * 16 + bh) * 2048 + nr];
    float m1 = Mm[(1 * 16 + bh) * 2048 + nr], l1 = Ll[(1 * 16 + bh) * 2048 + nr];
    float m2 = Mm[(2 * 16 + bh) * 2048 + nr], l2 = Ll[(2 * 16 + bh) * 2048 + nr];
    float m3 = Mm[(3 * 16 + bh) * 2048 + nr], l3 = Ll[(3 * 16 + bh) * 2048 + nr];
    float M = fmaxf(fmaxf(m0, m1), fmaxf(m2, m3));
    float w0 = l0 * exp2f(m0 - M), w1 = l1 * exp2f(m1 - M);
    float w2 = l2 * exp2f(m2 - M), w3 = l3 * exp2f(m3 - M);
    float inv = 1.f / (w0 + w1 + w2 + w3);
    w0 *= inv; w1 *= inv; w2 *= inv; w3 *= inv;
    float cb[16];
    {
      const short* p0 = &PO[((0 * 16 + bh) * 2048 + nr) * 64 + seg * 16];
      const short* p1 = &PO[((1 * 16 + bh) * 2048 + nr) * 64 + seg * 16];
      const short* p2 = &PO[((2 * 16 + bh) * 2048 + nr) * 64 + seg * 16];
      const short* p3 = &PO[((3 * 16 + bh) * 2048 + nr) * 64 + seg * 16];
      s16x8 a0 = *(const s16x8*)p0, a1 = *(const s16x8*)(p0 + 8);
      s16x8 b0 = *(const s16x8*)p1, b1 = *(const s16x8*)(p1 + 8);
      s16x8 c0 = *(const s16x8*)p2, c1 = *(const s16x8*)(p2 + 8);
      s16x8 d0 = *(const s16x8*)p3, d1 = *(const s16x8*)(p3 + 8);
#pragma unroll
      for (int j = 0; j < 8; ++j) {
        cb[j]     = w0 * h2f(a0[j]) + w1 * h2f(b0[j]) + w2 * h2f(c0[j]) + w3 * h2f(d0[j]);
        cb[j + 8] = w0 * h2f(a1[j]) + w1 * h2f(b1[j]) + w2 * h2f(c1[j]) + w3 * h2f(d1[j]);
      }
    }
    short hb[16];
#pragma unroll
    for (int j = 0; j < 16; ++j) hb[j] = f2h(cb[j]);
    *(s16x8*)((char*)Bs + swz128(row, seg * 2))     = *(const s16x8*)&hb[0];
    *(s16x8*)((char*)Bs + swz128(row, seg * 2 + 1)) = *(const s16x8*)&hb[8];
    __syncthreads();
#pragma unroll
    for (int ks = 0; ks < 2; ++ks) {
      f16x8 af[2], bfr[2];
#pragma unroll
      for (int f = 0; f < 2; ++f) {
        af[f]  = *(const f16x8*)((char*)As + swz128(wr * 32 + f * 16 + c, ks * 4 + g));
        bfr[f] = *(const f16x8*)((char*)Bs + swz128(wc * 32 + f * 16 + c, ks * 4 + g));
      }
#pragma unroll
      for (int i = 0; i < 2; ++i)
#pragma unroll
        for (int j = 0; j < 2; ++j)
          acc[i][j] = MFMA(af[i], bfr[j], acc[i][j]);
    }
  }
#pragma unroll
  for (int i = 0; i < 2; ++i) {
    int ob = o0 + wr * 32 + i * 16 + g * 4;
#pragma unroll
    for (int j = 0; j < 2; ++j) {
      int n = n0 + wc * 32 + j * 16 + c;
#pragma unroll
      for (int r = 0; r < 4; ++r)
        out[(b * 256 + ob + r) * 2048 + n] = acc[i][j][r] + bm[ob + r];
    }
  }
}

extern "C" void kernel_launch(void* const* d_in, const int* in_sizes, int n_in,
                              void* d_out, int out_size, void* d_ws, size_t ws_size,
                              hipStream_t stream) {
  (void)in_sizes; (void)n_in; (void)out_size; (void)ws_size;
  const float* q   = (const float*)d_in[0];
  const float* k   = (const float*)d_in[1];
  const float* v   = (const float*)d_in[2];
  const float* enc = (const float*)d_in[3];
  const float* Wq  = (const float*)d_in[4];
  const float* bq  = (const float*)d_in[5];
  const float* Wk  = (const float*)d_in[6];
  const float* bk  = (const float*)d_in[7];
  const float* Wv  = (const float*)d_in[8];
  const float* bv  = (const float*)d_in[9];
  const float* Wm  = (const float*)d_in[10];
  const float* bm  = (const float*)d_in[11];
  char* ws = (char*)d_ws;
  float* out = (float*)d_out;
  hipLaunchKernelGGL(k_trans, dim3(32, 4, 12), dim3(256), 0, stream, q, k, v, ws);
  hipLaunchKernelGGL(k_proj, dim3(32, 4, 12), dim3(256), 0, stream, Wq, Wk, Wv, enc, bq, bk, bv, ws);
  hipLaunchKernelGGL(k_attn, dim3(16, 16, 4), dim3(256), 0, stream, ws);
  hipLaunchKernelGGL(k_final, dim3(32, 4, 4), dim3(256), 0, stream, Wm, bm, out, ws);
}

// Round 10
// 161.945 us; speedup vs baseline: 1.0943x; 1.0943x over previous
//
#include <hip/hip_runtime.h>
#include <stdint.h>

#define NSEQ 2048

typedef __attribute__((ext_vector_type(4))) float f32x4;
typedef __attribute__((ext_vector_type(8))) short s16x8;
typedef _Float16 f16x8 __attribute__((ext_vector_type(8)));

// workspace byte offsets
#define OFF_XT  0u            // [3][4][2048][256] f16 = 12 MB (dead after k_proj)
#define OFF_PO  0u            // [4 split][16 bh][2048][64] f16 = 16 MB (aliases dead XT)
#define OFF_M   16777216u     // [4][16][2048] f32 running-max (log2 domain), 512 KB
#define OFF_L   17301504u     // [4][16][2048] f32 running-sum, 512 KB
#define OFF_QR  17825792u     // [16][2048][64] f16, 4 MB
#define OFF_KR  22020096u     // [16][2048][64]
#define OFF_VT  26214400u     // [16][64][2048]
#define OFF_W   30408704u     // 4 * 65536 f16 = 512 KB (ws end ~30.9 MB)

__device__ __forceinline__ short f2h(float f) {
  _Float16 h = (_Float16)f;
  return __builtin_bit_cast(short, h);
}
__device__ __forceinline__ float h2f(short s) {
  return (float)__builtin_bit_cast(_Float16, s);
}
// 128B-row tiles ([*][64] f16): classic ^(row&7) on the 16B slot
__device__ __forceinline__ int swz128(int row, int slot) {
  return row * 128 + ((slot ^ (row & 7)) << 4);
}
#define MFMA(a, b, c) __builtin_amdgcn_mfma_f32_16x16x32_f16(a, b, c, 0, 0, 0)

// ---------------- kernel 0: weight cast (+ Wm reorder to k = h*64+d) ----------------
__global__ void k_convw(const float* __restrict__ Wq, const float* __restrict__ Wk,
                        const float* __restrict__ Wv, const float* __restrict__ Wm,
                        char* __restrict__ ws) {
  int o = blockIdx.x, which = blockIdx.y, i = threadIdx.x;
  const float* src = which == 0 ? Wq : which == 1 ? Wk : which == 2 ? Wv : Wm;
  short* dst = (short*)(ws + OFF_W) + which * 65536;
  // Wm_r[o][h*64+d] = Wm[o][d*4+h]
  float val = (which < 3) ? src[o * 256 + i] : src[o * 256 + ((i & 63) << 2) + (i >> 6)];
  dst[o * 256 + i] = f2h(val);
}

// ---------------- kernel 1: transpose-cast q/k/v [b][i][n] f32 -> [b][n][i] f16 ------
__global__ __launch_bounds__(256) void k_trans(const float* __restrict__ q,
    const float* __restrict__ k, const float* __restrict__ v, char* __restrict__ ws) {
  int tensor = blockIdx.z >> 2, b = blockIdx.z & 3;
  const float* src = tensor == 0 ? q : (tensor == 1 ? k : v);
  short* dst = (short*)(ws + OFF_XT) + (tensor * 4 + b) * 524288;
  int n0 = blockIdx.x * 64, i0 = blockIdx.y * 64;
  __shared__ float tile[64][65];
  int t = threadIdx.x;
  int nl = t & 63, ib = (t >> 6) * 16;
#pragma unroll
  for (int r = 0; r < 16; ++r)
    tile[ib + r][nl] = src[(b * 256 + i0 + ib + r) * 2048 + n0 + nl];
  __syncthreads();
  int nr = t >> 2, ic = (t & 3) * 16;
  short tmp[16];
#pragma unroll
  for (int j = 0; j < 16; ++j) tmp[j] = f2h(tile[ic + j][nr]);
  short* dp = &dst[(n0 + nr) * 256 + i0 + ic];
  *(s16x8*)dp = *(const s16x8*)&tmp[0];
  *(s16x8*)(dp + 8) = *(const s16x8*)&tmp[8];
}

// ------- kernel 2: QKV projection (64x64 tile, f16 weights) + bias + RoPE -----------
// XCD chunk-swizzle: yo fastest so each XCD owns complete X-tile sibling groups
__global__ __launch_bounds__(256) void k_proj(const float* __restrict__ enc,
    const float* __restrict__ bq, const float* __restrict__ bk,
    const float* __restrict__ bv, char* __restrict__ ws) {
  int hid = blockIdx.x + 32 * (blockIdx.y + 4 * blockIdx.z);   // 0..1535
  int fm = (hid & 7) * 192 + (hid >> 3);                       // bijective (1536%8==0)
  int yo = fm & 3, xn = (fm >> 2) & 31, z = fm >> 7;
  int proj = z >> 2, b = z & 3;
  const short* W = (const short*)(ws + OFF_W) + proj * 65536;
  const short* X = (const short*)(ws + OFF_XT) + (proj * 4 + b) * 524288;
  int o0 = yo * 64, n0 = xn * 64;
  __shared__ short As[64 * 64], Bs[64 * 64];
  int t = threadIdx.x, lane = t & 63, g = lane >> 4, c = lane & 15, wave = t >> 6;
  int wr = wave >> 1, wc = wave & 1;
  int row = t >> 2, seg = t & 3;
  f32x4 acc[2][2] = {};
  for (int kk = 0; kk < 4; ++kk) {
    __syncthreads();
    int koff = kk * 64;
    const short* wsrc = &W[(o0 + row) * 256 + koff];
    const short* xsrc = &X[(n0 + row) * 256 + koff];
    *(s16x8*)((char*)As + swz128(row, seg))     = *(const s16x8*)(wsrc + seg * 8);
    *(s16x8*)((char*)As + swz128(row, 4 + seg)) = *(const s16x8*)(wsrc + 32 + seg * 8);
    *(s16x8*)((char*)Bs + swz128(row, seg))     = *(const s16x8*)(xsrc + seg * 8);
    *(s16x8*)((char*)Bs + swz128(row, 4 + seg)) = *(const s16x8*)(xsrc + 32 + seg * 8);
    __syncthreads();
#pragma unroll
    for (int ks = 0; ks < 2; ++ks) {
      f16x8 af[2], bfr[2];
#pragma unroll
      for (int f = 0; f < 2; ++f) {
        af[f]  = *(const f16x8*)((char*)As + swz128(wr * 32 + f * 16 + c, ks * 4 + g));
        bfr[f] = *(const f16x8*)((char*)Bs + swz128(wc * 32 + f * 16 + c, ks * 4 + g));
      }
#pragma unroll
      for (int i = 0; i < 2; ++i)
#pragma unroll
        for (int j = 0; j < 2; ++j)
          acc[i][j] = MFMA(af[i], bfr[j], acc[i][j]);
    }
  }
  const float* bias = proj == 0 ? bq : (proj == 1 ? bk : bv);
  if (proj < 2) {
    // RoPE: h = reg r, d = (o>>2); pair at lane^16, same reg.
    // fold 1/sqrt(64) * log2(e) into Q so softmax runs in exp2 domain
    short* dst0 = (short*)(ws + (proj == 0 ? OFF_QR : OFF_KR));
    float scale = proj == 0 ? 0.18033688f : 1.0f;
    float sgn = (g & 1) ? 1.0f : -1.0f;
#pragma unroll
    for (int i = 0; i < 2; ++i) {
      int ob = o0 + wr * 32 + i * 16 + g * 4;
      int d = ob >> 2;
#pragma unroll
      for (int j = 0; j < 2; ++j) {
        int n = n0 + wc * 32 + j * 16 + c;
        float cv = enc[n * 64 + d], sv = enc[131072 + n * 64 + d];
#pragma unroll
        for (int r = 0; r < 4; ++r) {
          float val = acc[i][j][r] + bias[ob + r];
          float par = __shfl_xor(val, 16, 64);
          float res = (val * cv + sgn * par * sv) * scale;
          dst0[((b * 4 + r) * 2048 + n) * 64 + d] = f2h(res);  // [bh][n][d]
        }
      }
    }
  } else {
    short* dst = (short*)(ws + OFF_VT);
#pragma unroll
    for (int i = 0; i < 2; ++i) {
      int ob = o0 + wr * 32 + i * 16 + g * 4;
      int d = ob >> 2;
#pragma unroll
      for (int j = 0; j < 2; ++j) {
        int n = n0 + wc * 32 + j * 16 + c;
#pragma unroll
        for (int r = 0; r < 4; ++r) {
          float val = acc[i][j][r] + bias[ob + r];
          dst[((b * 4 + r) * 64 + d) * 2048 + n] = f2h(val);  // [bh][d][m]
        }
      }
    }
  }
}

// ------- kernel 3: flash attention, split-KV x4, swapped QK^T (R7-proven base) ------
__global__ __launch_bounds__(256, 4) void k_attn(char* __restrict__ ws) {
  int bh = blockIdx.y, ms = blockIdx.z;
  int t = threadIdx.x, wave = t >> 6, lane = t & 63, g = lane >> 4, c = lane & 15;
  int nw = blockIdx.x * 64 + wave * 16;  // this wave's 16 Q rows
  const short* Q = (const short*)(ws + OFF_QR) + bh * 131072;  // [2048][64]
  const short* K = (const short*)(ws + OFF_KR) + bh * 131072;
  const short* V = (const short*)(ws + OFF_VT) + bh * 131072;  // [64][2048]
  __shared__ short Ks[64 * 64], Vs[64 * 64], Ps[4][16 * 64];
  char* Pb = (char*)Ps[wave];
  f16x8 qf0 = *(const f16x8*)&Q[(nw + c) * 64 + g * 8];
  f16x8 qf1 = *(const f16x8*)&Q[(nw + c) * 64 + 32 + g * 8];
  f32x4 po[4] = {};
  float mrun = -1e30f, lrun = 0.f;   // per-lane scalars: softmax state of q-row (nw+c)
  int sr = t >> 3, sl = t & 7;
  const int mb = ms * 512;
  int bsrc = g * 16 + g * 4;         // shfl base: lane in same g-group holding row g*4+r

  s16x8 RA[4], RB[4];
  auto LD = [&](int m0, s16x8* R) {
    R[0] = *(const s16x8*)&K[(m0 + sr) * 64 + sl * 8];
    R[1] = *(const s16x8*)&K[(m0 + sr + 32) * 64 + sl * 8];
    R[2] = *(const s16x8*)&V[sr * 2048 + m0 + sl * 8];
    R[3] = *(const s16x8*)&V[(sr + 32) * 2048 + m0 + sl * 8];
  };
  auto ST = [&](const s16x8* R) {
    *(s16x8*)((char*)Ks + swz128(sr, sl))      = R[0];
    *(s16x8*)((char*)Ks + swz128(sr + 32, sl)) = R[1];
    *(s16x8*)((char*)Vs + swz128(sr, sl))      = R[2];
    *(s16x8*)((char*)Vs + swz128(sr + 32, sl)) = R[3];
  };
  auto COMPUTE = [&]() {
    // S^T = K Q^T : row = m = fj*16 + g*4 + r, col = n = c (lane-local q-row!)
    f32x4 s[4] = {};
    __builtin_amdgcn_s_setprio(1);
#pragma unroll
    for (int fj = 0; fj < 4; ++fj) {
      f16x8 k0 = *(const f16x8*)((char*)Ks + swz128(fj * 16 + c, g));
      f16x8 k1 = *(const f16x8*)((char*)Ks + swz128(fj * 16 + c, 4 + g));
      s[fj] = MFMA(k0, qf0, s[fj]);
      s[fj] = MFMA(k1, qf1, s[fj]);
    }
    __builtin_amdgcn_s_setprio(0);
    // row-max: in-register tree over 16, then 2 cross-lane rounds (xor16, xor32)
    float t0 = fmaxf(fmaxf(s[0][0], s[0][1]), fmaxf(s[0][2], s[0][3]));
    float t1 = fmaxf(fmaxf(s[1][0], s[1][1]), fmaxf(s[1][2], s[1][3]));
    float t2 = fmaxf(fmaxf(s[2][0], s[2][1]), fmaxf(s[2][2], s[2][3]));
    float t3 = fmaxf(fmaxf(s[3][0], s[3][1]), fmaxf(s[3][2], s[3][3]));
    float rmax = fmaxf(fmaxf(t0, t1), fmaxf(t2, t3));
    rmax = fmaxf(rmax, __shfl_xor(rmax, 16, 64));
    rmax = fmaxf(rmax, __shfl_xor(rmax, 32, 64));
    // defer-max: only rescale when the running max grows materially (exp2 domain)
    if (__any(rmax > mrun + 11.5f)) {
      float nm = fmaxf(mrun, rmax);
      float corr = exp2f(mrun - nm);
      mrun = nm;
      lrun *= corr;
#pragma unroll
      for (int r = 0; r < 4; ++r) {
        float corr_r = __shfl(corr, bsrc + r, 64);  // corr of row g*4+r
#pragma unroll
        for (int fd = 0; fd < 4; ++fd) po[fd][r] *= corr_r;
      }
    }
    float p[4][4], rs = 0.f;
#pragma unroll
    for (int fj = 0; fj < 4; ++fj) {
      f32x4 pv;
#pragma unroll
      for (int r = 0; r < 4; ++r) {
        pv[r] = exp2f(s[fj][r] - mrun);
        p[fj][r] = pv[r];
      }
      rs += (pv[0] + pv[1]) + (pv[2] + pv[3]);
    }
    rs += __shfl_xor(rs, 16, 64);
    rs += __shfl_xor(rs, 32, 64);
    lrun += rs;
    // P^T -> Ps as P[n=c][m] rows (A-frag layout for PV)
#pragma unroll
    for (int fj = 0; fj < 4; ++fj)
#pragma unroll
      for (int r = 0; r < 4; ++r) {
        int mm = fj * 16 + g * 4 + r;
        *(short*)(Pb + swz128(c, mm >> 3) + (mm & 7) * 2) = f2h(p[fj][r]);
      }
    asm volatile("s_waitcnt lgkmcnt(0)" ::: "memory");
    __builtin_amdgcn_sched_barrier(0);
    f16x8 pa0 = *(const f16x8*)(Pb + swz128(c, g));
    f16x8 pa1 = *(const f16x8*)(Pb + swz128(c, 4 + g));
    __builtin_amdgcn_s_setprio(1);
#pragma unroll
    for (int fd = 0; fd < 4; ++fd) {
      int dd = fd * 16 + c;
      f16x8 vb0 = *(const f16x8*)((char*)Vs + swz128(dd, g));
      f16x8 vb1 = *(const f16x8*)((char*)Vs + swz128(dd, 4 + g));
      po[fd] = MFMA(pa0, vb0, po[fd]);
      po[fd] = MFMA(pa1, vb1, po[fd]);
    }
    __builtin_amdgcn_s_setprio(0);
  };

  LD(mb, RA);
  for (int tt = 0; tt < 8; tt += 2) {
    __syncthreads();                 // prior tile's LDS reads complete
    ST(RA);
    LD(mb + (tt + 1) * 64, RB);      // prefetch hides under compute
    __syncthreads();
    COMPUTE();
    __syncthreads();
    ST(RB);
    if (tt + 2 < 8) LD(mb + (tt + 2) * 64, RA);
    __syncthreads();
    COMPUTE();
  }

  // epilogue: normalize, transpose through per-wave LDS, vector-store PO rows
  short* PO = (short*)(ws + OFF_PO);
  float* Mm = (float*)(ws + OFF_M);
  float* Ll = (float*)(ws + OFF_L);
  int base = (ms * 16 + bh) * 2048;
  float li[4];
#pragma unroll
  for (int r = 0; r < 4; ++r) li[r] = 1.0f / __shfl(lrun, bsrc + r, 64);
  asm volatile("s_waitcnt lgkmcnt(0)" ::: "memory");  // Pb reads from last COMPUTE done
  __builtin_amdgcn_sched_barrier(0);
#pragma unroll
  for (int fd = 0; fd < 4; ++fd) {
    int d = fd * 16 + c;
#pragma unroll
    for (int r = 0; r < 4; ++r)
      *(short*)(Pb + swz128(g * 4 + r, d >> 3) + (d & 7) * 2) = f2h(po[fd][r] * li[r]);
  }
  asm volatile("s_waitcnt lgkmcnt(0)" ::: "memory");
  __builtin_amdgcn_sched_barrier(0);
  int rr = lane >> 2, ds = (lane & 3) * 16;
  s16x8 v0 = *(const s16x8*)(Pb + swz128(rr, ds >> 3));
  s16x8 v1 = *(const s16x8*)(Pb + swz128(rr, (ds >> 3) + 1));
  *(s16x8*)&PO[(base + nw + rr) * 64 + ds]     = v0;
  *(s16x8*)&PO[(base + nw + rr) * 64 + ds + 8] = v1;
  if (g == 0) {
    Mm[base + nw + c] = mrun;
    Ll[base + nw + c] = lrun;
  }
}

// ------- kernel 4: output projection (64x32), f16 Wm_r, combine fused in B-staging --
__global__ __launch_bounds__(256) void k_final(const float* __restrict__ bm,
    float* __restrict__ out, char* __restrict__ ws) {
  int hid = blockIdx.x + 64 * (blockIdx.y + 4 * blockIdx.z);   // 0..1023
  int fm = (hid & 7) * 128 + (hid >> 3);                       // bijective (1024%8==0)
  int yo = fm & 3, xn = (fm >> 2) & 63, b = fm >> 8;
  int o0 = yo * 64, n0 = xn * 32;
  const short* Wf = (const short*)(ws + OFF_W) + 3 * 65536;    // Wm reordered f16
  const short* PO = (const short*)(ws + OFF_PO);
  const float* Mm = (const float*)(ws + OFF_M);
  const float* Ll = (const float*)(ws + OFF_L);
  __shared__ short As[64 * 64], Bs[32 * 64];
  int t = threadIdx.x, lane = t & 63, g = lane >> 4, c = lane & 15, wave = t >> 6;
  int wr = wave >> 1, wc = wave & 1;
  int arow = t >> 2, aseg = t & 3;
  int brow = t >> 3, bseg = t & 7;
  f32x4 acc[2] = {};
  for (int kk = 0; kk < 4; ++kk) {   // kk = head h; local k = d within head
    __syncthreads();
    // A: f16 Wm_r, coalesced
    const short* wsrc = &Wf[(o0 + arow) * 256 + kk * 64];
    *(s16x8*)((char*)As + swz128(arow, aseg))     = *(const s16x8*)(wsrc + aseg * 8);
    *(s16x8*)((char*)As + swz128(arow, 4 + aseg)) = *(const s16x8*)(wsrc + 32 + aseg * 8);
    // B: combine 4 KV-split partials for row n0+brow, head kk, d = bseg*8..+8
    int bh = b * 4 + kk;
    int nr = n0 + brow;
    float m0 = Mm[(0 * 16 + bh) * 2048 + nr], l0 = Ll[(0 * 16 + bh) * 2048 + nr];
    float m1 = Mm[(1 * 16 + bh) * 2048 + nr], l1 = Ll[(1 * 16 + bh) * 2048 + nr];
    float m2 = Mm[(2 * 16 + bh) * 2048 + nr], l2 = Ll[(2 * 16 + bh) * 2048 + nr];
    float m3 = Mm[(3 * 16 + bh) * 2048 + nr], l3 = Ll[(3 * 16 + bh) * 2048 + nr];
    float M = fmaxf(fmaxf(m0, m1), fmaxf(m2, m3));
    float w0 = l0 * exp2f(m0 - M), w1 = l1 * exp2f(m1 - M);
    float w2 = l2 * exp2f(m2 - M), w3 = l3 * exp2f(m3 - M);
    float inv = 1.f / (w0 + w1 + w2 + w3);
    w0 *= inv; w1 *= inv; w2 *= inv; w3 *= inv;
    s16x8 a0 = *(const s16x8*)&PO[((0 * 16 + bh) * 2048 + nr) * 64 + bseg * 8];
    s16x8 a1 = *(const s16x8*)&PO[((1 * 16 + bh) * 2048 + nr) * 64 + bseg * 8];
    s16x8 a2 = *(const s16x8*)&PO[((2 * 16 + bh) * 2048 + nr) * 64 + bseg * 8];
    s16x8 a3 = *(const s16x8*)&PO[((3 * 16 + bh) * 2048 + nr) * 64 + bseg * 8];
    short hb[8];
#pragma unroll
    for (int j = 0; j < 8; ++j)
      hb[j] = f2h(w0 * h2f(a0[j]) + w1 * h2f(a1[j]) + w2 * h2f(a2[j]) + w3 * h2f(a3[j]));
    *(s16x8*)((char*)Bs + swz128(brow, bseg)) = *(const s16x8*)hb;
    __syncthreads();
#pragma unroll
    for (int ks = 0; ks < 2; ++ks) {
      f16x8 af[2], bfr;
#pragma unroll
      for (int f = 0; f < 2; ++f)
        af[f] = *(const f16x8*)((char*)As + swz128(wr * 32 + f * 16 + c, ks * 4 + g));
      bfr = *(const f16x8*)((char*)Bs + swz128(wc * 16 + c, ks * 4 + g));
#pragma unroll
      for (int i = 0; i < 2; ++i)
        acc[i] = MFMA(af[i], bfr, acc[i]);
    }
  }
#pragma unroll
  for (int i = 0; i < 2; ++i) {
    int ob = o0 + wr * 32 + i * 16 + g * 4;
    int n = n0 + wc * 16 + c;
#pragma unroll
    for (int r = 0; r < 4; ++r)
      out[(b * 256 + ob + r) * 2048 + n] = acc[i][r] + bm[ob + r];
  }
}

extern "C" void kernel_launch(void* const* d_in, const int* in_sizes, int n_in,
                              void* d_out, int out_size, void* d_ws, size_t ws_size,
                              hipStream_t stream) {
  (void)in_sizes; (void)n_in; (void)out_size; (void)ws_size;
  const float* q   = (const float*)d_in[0];
  const float* k   = (const float*)d_in[1];
  const float* v   = (const float*)d_in[2];
  const float* enc = (const float*)d_in[3];
  const float* Wq  = (const float*)d_in[4];
  const float* bq  = (const float*)d_in[5];
  const float* Wk  = (const float*)d_in[6];
  const float* bk  = (const float*)d_in[7];
  const float* Wv  = (const float*)d_in[8];
  const float* bv  = (const float*)d_in[9];
  const float* Wm  = (const float*)d_in[10];
  const float* bm  = (const float*)d_in[11];
  char* ws = (char*)d_ws;
  float* out = (float*)d_out;
  hipLaunchKernelGGL(k_convw, dim3(256, 4), dim3(256), 0, stream, Wq, Wk, Wv, Wm, ws);
  hipLaunchKernelGGL(k_trans, dim3(32, 4, 12), dim3(256), 0, stream, q, k, v, ws);
  hipLaunchKernelGGL(k_proj, dim3(32, 4, 12), dim3(256), 0, stream, enc, bq, bk, bv, ws);
  hipLaunchKernelGGL(k_attn, dim3(32, 16, 4), dim3(256), 0, stream, ws);
  hipLaunchKernelGGL(k_final, dim3(64, 4, 4), dim3(256), 0, stream, bm, out, ws);
}